// Round 1
// baseline (534.316 us; speedup 1.0000x reference)
//
#include <hip/hip_runtime.h>
#include <hip/hip_bf16.h>
#include <stdint.h>

#define B_ 2
#define S_ 2048
#define H_ 1024
#define I_ 2048
#define E_ 8
#define TOK (B_*S_)      // 4096 tokens
#define PAIRS (TOK*2)    // 8192 token-expert pairs
#define MAXBLK 40        // max sum_e ceil(cnt_e/256) = 32+7=39

typedef __bf16 bf16_t;
typedef __bf16 bf16x4 __attribute__((ext_vector_type(4)));
typedef __bf16 bf16x8 __attribute__((ext_vector_type(8)));
typedef float  f32x4  __attribute__((ext_vector_type(4)));
typedef float  f32x16 __attribute__((ext_vector_type(16)));

// async global->LDS, 16B per lane. LDS dest = wave-uniform base + lane*16.
__device__ __forceinline__ void gl_lds16(const bf16_t* g, bf16_t* l) {
    __builtin_amdgcn_global_load_lds(
        (const __attribute__((address_space(1))) unsigned int*)g,
        (__attribute__((address_space(3))) unsigned int*)l, 16, 0, 0);
}

// ---------------- Router (+ x -> bf16 cast fused) ----------------
__global__ void router_kernel(const float* __restrict__ x, const float* __restrict__ Wg,
                              int* __restrict__ top2e, float* __restrict__ top2w,
                              int* __restrict__ counts, bf16_t* __restrict__ xb) {
    int wave = threadIdx.x >> 6;
    int lane = threadIdx.x & 63;
    int t = blockIdx.x * 4 + wave;
    if (t >= TOK) return;
    float acc[E_];
#pragma unroll
    for (int e = 0; e < E_; e++) acc[e] = 0.f;
    const float* xrow = x + (size_t)t * H_;
    for (int j = 0; j < H_ / 64; j++) {
        int h = j * 64 + lane;
        float xv = xrow[h];
        const float4* wg = (const float4*)(Wg + (size_t)h * E_);
        float4 w0 = wg[0], w1 = wg[1];
        acc[0] += xv * w0.x; acc[1] += xv * w0.y; acc[2] += xv * w0.z; acc[3] += xv * w0.w;
        acc[4] += xv * w1.x; acc[5] += xv * w1.y; acc[6] += xv * w1.z; acc[7] += xv * w1.w;
    }
    // fused cast: write this token's bf16 row (re-read hits L1/L2)
#pragma unroll
    for (int part = 0; part < 2; part++) {
        int idx = part * 512 + lane * 8;
        float4 v0 = *(const float4*)(xrow + idx);
        float4 v1 = *(const float4*)(xrow + idx + 4);
        bf16x8 ov = { (bf16_t)v0.x, (bf16_t)v0.y, (bf16_t)v0.z, (bf16_t)v0.w,
                      (bf16_t)v1.x, (bf16_t)v1.y, (bf16_t)v1.z, (bf16_t)v1.w };
        *(bf16x8*)(xb + (size_t)t * H_ + idx) = ov;
    }
#pragma unroll
    for (int e = 0; e < E_; e++) {
#pragma unroll
        for (int m = 32; m >= 1; m >>= 1) acc[e] += __shfl_xor(acc[e], m, 64);
    }
    if (lane == 0) {
        float mx = acc[0];
        for (int e = 1; e < E_; e++) mx = fmaxf(mx, acc[e]);
        float p[E_]; float z = 0.f;
        for (int e = 0; e < E_; e++) { p[e] = __expf(acc[e] - mx); z += p[e]; }
        for (int e = 0; e < E_; e++) p[e] /= z;
        int i1 = 0; float p1 = p[0];
        for (int e = 1; e < E_; e++) if (p[e] > p1) { p1 = p[e]; i1 = e; }
        int i2 = -1; float p2 = -1.f;
        for (int e = 0; e < E_; e++) if (e != i1 && p[e] > p2) { p2 = p[e]; i2 = e; }
        float s = p1 + p2 + 1e-8f;
        top2e[t * 2]     = i1; top2e[t * 2 + 1] = i2;
        top2w[t * 2]     = p1 / s; top2w[t * 2 + 1] = p2 / s;
        atomicAdd(&counts[i1], 1);
        atomicAdd(&counts[i2], 1);
    }
}

// ---------------- scan + fill in one block (LDS cursors) ----------------
__global__ __launch_bounds__(256) void scanfill_kernel(
    const int* __restrict__ counts, int* __restrict__ offsets,
    int* __restrict__ blk_e, int* __restrict__ blk_m0, int* __restrict__ nblk,
    const int* __restrict__ top2e, int* __restrict__ pair_tok, int* __restrict__ inv) {
    __shared__ int s_cur[E_];
    if (threadIdx.x == 0) {
        int run = 0, b = 0;
        for (int e = 0; e < E_; e++) {
            offsets[e] = run; s_cur[e] = run;
            int c = counts[e];
            for (int m0 = 0; m0 < c; m0 += 256) { blk_e[b] = e; blk_m0[b] = m0; b++; }
            run += c;
        }
        nblk[0] = b;
    }
    __syncthreads();
    for (int p = threadIdx.x; p < PAIRS; p += 256) {
        int e = top2e[p];
        int pos = atomicAdd(&s_cur[e], 1);
        pair_tok[pos] = p >> 1;
        inv[p] = pos;
    }
}

// ---------------- merged weight transpose-cast ----------------
// z = w*E+e, w in {0:W11, 1:W12, 2:W2}. src [R][C] fp32 -> dst [C][R] bf16.
__global__ __launch_bounds__(256) void wtrans_kernel(
    const float* __restrict__ W11, const float* __restrict__ W12,
    const float* __restrict__ W2,
    bf16_t* __restrict__ W11t, bf16_t* __restrict__ W12t, bf16_t* __restrict__ W2t) {
    __shared__ float tile[64][129];
    int z = blockIdx.y;
    int wsel = z >> 3, e = z & 7;
    const float* sbase; bf16_t* dbase; int R, C, tx, ty;
    if (wsel == 0)      { sbase = W11; dbase = W11t; R = H_; C = I_; }
    else if (wsel == 1) { sbase = W12; dbase = W12t; R = H_; C = I_; }
    else                { sbase = W2;  dbase = W2t;  R = I_; C = H_; }
    if (wsel < 2) { tx = blockIdx.x & 15; ty = blockIdx.x >> 4; }   // 16 x 16
    else          { tx = blockIdx.x & 7;  ty = blockIdx.x >> 3; }   // 8 x 32
    const float* s = sbase + (size_t)e * R * C;
    bf16_t* d = dbase + (size_t)e * R * C;
    int c0 = tx * 128, r0 = ty * 64;
    int t = threadIdx.x;
#pragma unroll
    for (int j = 0; j < 8; j++) {
        int flat = j * 256 + t;          // 0..2047
        int r = flat >> 5;               // 0..63
        int c4 = (flat & 31) * 4;        // 0..124
        float4 v = *(const float4*)(s + (size_t)(r0 + r) * C + c0 + c4);
        tile[r][c4 + 0] = v.x;
        tile[r][c4 + 1] = v.y;
        tile[r][c4 + 2] = v.z;
        tile[r][c4 + 3] = v.w;
    }
    __syncthreads();
#pragma unroll
    for (int j = 0; j < 4; j++) {
        int flat = j * 256 + t;          // 0..1023
        int orow = flat >> 3;            // 0..127 (src col)
        int seg  = (flat & 7) * 8;       // 0..56 (src row base)
        bf16x8 v;
#pragma unroll
        for (int k = 0; k < 8; k++) v[k] = (bf16_t)tile[seg + k][orow];
        *(bf16x8*)(d + (size_t)(c0 + orow) * R + r0 + seg) = v;
    }
}

// ---------------- GEMM1: fused = SiLU(x@W11) * (x@W12) ----------------
// 512 thr / 8 waves, BM=256 tokens x 128 i-cols (256 B-rows: per 32-col group,
// rows g*64+[0,32) = gate (W11t), g*64+[32,64) = value (W12t)).
// Double-buffered LDS (128 KB), counted vmcnt(8), 4 phases/K-tile, setprio.
#define G1_LDSE ((256 + 256) * 64)   // elems per buffer

__global__ __launch_bounds__(512, 2) void gemm1_kernel(
    const bf16_t* __restrict__ xb,       // [TOK][H]
    const bf16_t* __restrict__ W11t,     // [E][I][H]
    const bf16_t* __restrict__ W12t,     // [E][I][H]
    const int* __restrict__ counts, const int* __restrict__ offsets,
    const int* __restrict__ blk_e, const int* __restrict__ blk_m0,
    const int* __restrict__ nblk,
    const int* __restrict__ pair_tok,
    bf16_t* __restrict__ fused)          // [PAIRS][I]
{
    int by = blockIdx.y;
    if (by >= nblk[0]) return;
    int e = blk_e[by];
    int m0 = blk_m0[by];
    int cnt = counts[e];
    int off = offsets[e];
    int n0 = blockIdx.x * 128;           // i-col base

    extern __shared__ __align__(16) bf16_t smem[];   // 2 * G1_LDSE

    int tid = threadIdx.x;
    int w = tid >> 6, lane = tid & 63;
    int wm = w >> 2, wn = w & 3;          // wave tile: M 128 (wm) x Brow 64 (wn)
    int lrow = lane >> 3, lcol = lane & 7;
    int scol = lcol ^ lrow;               // pre-swizzled global slot
    int r32 = lane & 31, khalf = lane >> 5, rx = r32 & 7;
    int rbase = w * 8 + lrow;             // 0..63

    const bf16_t* aptr[4];
    const bf16_t* bptr[4];
#pragma unroll
    for (int it = 0; it < 4; it++) {
        int arow = it * 64 + rbase;       // 0..255
        int grow = m0 + arow;
        int tok = pair_tok[off + (grow < cnt ? grow : 0)];
        aptr[it] = xb + (size_t)tok * H_ + scol * 8;
        // B row = it*64 + rbase: colgroup it, gate if rbase<32 else value
        int wrow = n0 + it * 32 + (rbase & 31);
        const bf16_t* wb = (rbase < 32) ? W11t : W12t;
        bptr[it] = wb + ((size_t)e * I_ + wrow) * H_ + scol * 8;
    }

    f32x16 accg[4], accv[4];
#pragma unroll
    for (int m = 0; m < 4; m++) { accg[m] = (f32x16)(0.f); accv[m] = (f32x16)(0.f); }

    // stage tile 0 into buf0
    {
        bf16_t* An = smem;
        bf16_t* Bn = smem + 256 * 64;
#pragma unroll
        for (int it = 0; it < 4; it++) gl_lds16(aptr[it], &An[(it * 64 + w * 8) * 64]);
#pragma unroll
        for (int it = 0; it < 4; it++) gl_lds16(bptr[it], &Bn[(it * 64 + w * 8) * 64]);
    }

    const int NT = H_ / 64;               // 16 K-tiles
    for (int t = 0; t < NT; t++) {
        bf16_t* Ac = smem + (t & 1) * G1_LDSE;
        bf16_t* Bc = Ac + 256 * 64;
        if (t + 1 < NT) {
            bf16_t* An = smem + ((t + 1) & 1) * G1_LDSE;
            bf16_t* Bn = An + 256 * 64;
            int ko = (t + 1) * 64;
#pragma unroll
            for (int it = 0; it < 4; it++) gl_lds16(aptr[it] + ko, &An[(it * 64 + w * 8) * 64]);
#pragma unroll
            for (int it = 0; it < 4; it++) gl_lds16(bptr[it] + ko, &Bn[(it * 64 + w * 8) * 64]);
            // counted: keep the 8 loads of tile t+1 in flight, wait only tile t's
            asm volatile("s_waitcnt vmcnt(8)" ::: "memory");
        } else {
            asm volatile("s_waitcnt vmcnt(0)" ::: "memory");
        }
        __builtin_amdgcn_s_barrier();
#pragma unroll
        for (int p = 0; p < 4; p++) {     // phase = one K16 segment
            int slot = p * 2 + khalf;
            bf16x8 af[4], bfr[2];
#pragma unroll
            for (int ms = 0; ms < 4; ms++) {
                int row = wm * 128 + ms * 32 + r32;
                af[ms] = *(const bf16x8*)&Ac[row * 64 + ((slot ^ rx)) * 8];
            }
            {
                int rg = wn * 64 + r32;
                bfr[0] = *(const bf16x8*)&Bc[rg * 64 + (slot ^ rx) * 8];
                bfr[1] = *(const bf16x8*)&Bc[(rg + 32) * 64 + (slot ^ rx) * 8];
            }
            __builtin_amdgcn_s_barrier();
            asm volatile("s_waitcnt lgkmcnt(0)" ::: "memory");
            __builtin_amdgcn_sched_barrier(0);
            __builtin_amdgcn_s_setprio(1);
#pragma unroll
            for (int ms = 0; ms < 4; ms++)
                accg[ms] = __builtin_amdgcn_mfma_f32_32x32x16_bf16(af[ms], bfr[0], accg[ms], 0, 0, 0);
#pragma unroll
            for (int ms = 0; ms < 4; ms++)
                accv[ms] = __builtin_amdgcn_mfma_f32_32x32x16_bf16(af[ms], bfr[1], accv[ms], 0, 0, 0);
            __builtin_amdgcn_s_setprio(0);
            __builtin_amdgcn_sched_barrier(0);
            __builtin_amdgcn_s_barrier();
        }
    }

    // C/D 32x32 layout: col=lane&31, row=(reg&3)+8*(reg>>2)+4*(lane>>5)
    int i = n0 + wn * 32 + r32;
#pragma unroll
    for (int ms = 0; ms < 4; ms++) {
#pragma unroll
        for (int reg = 0; reg < 16; reg++) {
            int rrow = (reg & 3) + 8 * (reg >> 2) + 4 * khalf;
            int grow = m0 + wm * 128 + ms * 32 + rrow;
            if (grow < cnt) {
                float g = accg[ms][reg];
                float v = accv[ms][reg];
                float f = g * v / (1.f + __expf(-g));
                fused[(size_t)(off + grow) * I_ + i] = (bf16_t)f;
            }
        }
    }
}

// ---------------- GEMM2: y[slot] = fused[slot] @ W2, bf16 out ----------------
// 512 thr / 8 waves, BM=256 x BN=128, K=I. Same dbuf/counted-vmcnt template.
#define G2_LDSE ((256 + 128) * 64)

__global__ __launch_bounds__(512, 2) void gemm2_kernel(
    const bf16_t* __restrict__ fused,    // [PAIRS][I]
    const bf16_t* __restrict__ W2t,      // [E][H][I]
    const int* __restrict__ counts, const int* __restrict__ offsets,
    const int* __restrict__ blk_e, const int* __restrict__ blk_m0,
    const int* __restrict__ nblk,
    bf16_t* __restrict__ y)              // [PAIRS][H]
{
    int by = blockIdx.y;
    if (by >= nblk[0]) return;
    int e = blk_e[by];
    int m0 = blk_m0[by];
    int cnt = counts[e];
    int off = offsets[e];
    int n0 = blockIdx.x * 128;

    extern __shared__ __align__(16) bf16_t smem[];   // 2 * G2_LDSE

    int tid = threadIdx.x;
    int w = tid >> 6, lane = tid & 63;
    int wm = w >> 1, wn = w & 1;          // wave tile: M 64 (wm) x N 64 (wn)
    int lrow = lane >> 3, lcol = lane & 7;
    int scol = lcol ^ lrow;
    int r32 = lane & 31, khalf = lane >> 5, rx = r32 & 7;
    int rbase = w * 8 + lrow;

    const bf16_t* aptr[4];
    const bf16_t* bptr[2];
#pragma unroll
    for (int it = 0; it < 4; it++) {
        int grow = m0 + it * 64 + rbase;
        if (grow >= cnt) grow = cnt - 1;
        aptr[it] = fused + (size_t)(off + grow) * I_ + scol * 8;
    }
#pragma unroll
    for (int it = 0; it < 2; it++) {
        int row = it * 64 + rbase;        // 0..127
        bptr[it] = W2t + ((size_t)e * H_ + n0 + row) * I_ + scol * 8;
    }

    f32x16 acc[2][2];
#pragma unroll
    for (int a = 0; a < 2; a++)
#pragma unroll
        for (int b = 0; b < 2; b++) acc[a][b] = (f32x16)(0.f);

    // stage tile 0
    {
        bf16_t* An = smem;
        bf16_t* Bn = smem + 256 * 64;
#pragma unroll
        for (int it = 0; it < 4; it++) gl_lds16(aptr[it], &An[(it * 64 + w * 8) * 64]);
#pragma unroll
        for (int it = 0; it < 2; it++) gl_lds16(bptr[it], &Bn[(it * 64 + w * 8) * 64]);
    }

    const int NT = I_ / 64;               // 32 K-tiles
    for (int t = 0; t < NT; t++) {
        bf16_t* Ac = smem + (t & 1) * G2_LDSE;
        bf16_t* Bc = Ac + 256 * 64;
        if (t + 1 < NT) {
            bf16_t* An = smem + ((t + 1) & 1) * G2_LDSE;
            bf16_t* Bn = An + 256 * 64;
            int ko = (t + 1) * 64;
#pragma unroll
            for (int it = 0; it < 4; it++) gl_lds16(aptr[it] + ko, &An[(it * 64 + w * 8) * 64]);
#pragma unroll
            for (int it = 0; it < 2; it++) gl_lds16(bptr[it] + ko, &Bn[(it * 64 + w * 8) * 64]);
            asm volatile("s_waitcnt vmcnt(6)" ::: "memory");
        } else {
            asm volatile("s_waitcnt vmcnt(0)" ::: "memory");
        }
        __builtin_amdgcn_s_barrier();
#pragma unroll
        for (int p2 = 0; p2 < 2; p2++) {  // phase = K32 (two K16 segs)
            bf16x8 af[2][2], bfr[2][2];
#pragma unroll
            for (int sub = 0; sub < 2; sub++) {
                int slot = p2 * 4 + sub * 2 + khalf;
#pragma unroll
                for (int ms = 0; ms < 2; ms++) {
                    int row = wm * 64 + ms * 32 + r32;
                    af[sub][ms] = *(const bf16x8*)&Ac[row * 64 + (slot ^ rx) * 8];
                }
#pragma unroll
                for (int ns = 0; ns < 2; ns++) {
                    int row = wn * 64 + ns * 32 + r32;
                    bfr[sub][ns] = *(const bf16x8*)&Bc[row * 64 + (slot ^ rx) * 8];
                }
            }
            __builtin_amdgcn_s_barrier();
            asm volatile("s_waitcnt lgkmcnt(0)" ::: "memory");
            __builtin_amdgcn_sched_barrier(0);
            __builtin_amdgcn_s_setprio(1);
#pragma unroll
            for (int sub = 0; sub < 2; sub++)
#pragma unroll
                for (int ms = 0; ms < 2; ms++)
#pragma unroll
                    for (int ns = 0; ns < 2; ns++)
                        acc[ms][ns] = __builtin_amdgcn_mfma_f32_32x32x16_bf16(
                            af[sub][ms], bfr[sub][ns], acc[ms][ns], 0, 0, 0);
            __builtin_amdgcn_s_setprio(0);
            __builtin_amdgcn_sched_barrier(0);
            __builtin_amdgcn_s_barrier();
        }
    }

#pragma unroll
    for (int ms = 0; ms < 2; ms++) {
#pragma unroll
        for (int reg = 0; reg < 16; reg++) {
            int rrow = (reg & 3) + 8 * (reg >> 2) + 4 * khalf;
            int grow = m0 + wm * 64 + ms * 32 + rrow;
            if (grow < cnt) {
                int slot = off + grow;
#pragma unroll
                for (int ns = 0; ns < 2; ns++) {
                    int h = n0 + wn * 64 + ns * 32 + r32;
                    y[(size_t)slot * H_ + h] = (bf16_t)acc[ms][ns][reg];
                }
            }
        }
    }
}

// ---------------- combine: out[t] = w1*y[s1] + w2*y[s2] ----------------
__global__ __launch_bounds__(256) void combine_kernel(
    const bf16_t* __restrict__ y, const int* __restrict__ inv,
    const float* __restrict__ top2w, float* __restrict__ out) {
    int t = blockIdx.x;
    int h = threadIdx.x * 4;
    int s1 = inv[t * 2], s2 = inv[t * 2 + 1];
    float w1 = top2w[t * 2], w2 = top2w[t * 2 + 1];
    bf16x4 a = *(const bf16x4*)(y + (size_t)s1 * H_ + h);
    bf16x4 b = *(const bf16x4*)(y + (size_t)s2 * H_ + h);
    f32x4 r;
#pragma unroll
    for (int k = 0; k < 4; k++) r[k] = w1 * (float)a[k] + w2 * (float)b[k];
    *(f32x4*)(out + (size_t)t * H_ + h) = r;
}

// ---------------- host ----------------
extern "C" void kernel_launch(void* const* d_in, const int* in_sizes, int n_in,
                              void* d_out, int out_size, void* d_ws, size_t ws_size,
                              hipStream_t stream) {
    const float* x   = (const float*)d_in[0];
    const float* Wg  = (const float*)d_in[1];
    const float* W11 = (const float*)d_in[2];
    const float* W12 = (const float*)d_in[3];
    const float* W2  = (const float*)d_in[4];
    float* out = (float*)d_out;

    char* ws = (char*)d_ws;
    size_t o = 0;
    auto alloc = [&](size_t bytes) { size_t r = o; o = (o + bytes + 255) & ~(size_t)255; return r; };
    int*    counts   = (int*)(ws + alloc(E_ * 4));
    int*    offsets  = (int*)(ws + alloc(E_ * 4));
    int*    blk_e    = (int*)(ws + alloc(MAXBLK * 4));
    int*    blk_m0   = (int*)(ws + alloc(MAXBLK * 4));
    int*    nblk     = (int*)(ws + alloc(4));
    int*    top2e    = (int*)(ws + alloc(TOK * 2 * 4));
    float*  top2w    = (float*)(ws + alloc(TOK * 2 * 4));
    int*    pair_tok = (int*)(ws + alloc(PAIRS * 4));
    int*    inv      = (int*)(ws + alloc(TOK * 2 * 4));
    bf16_t* xb       = (bf16_t*)(ws + alloc((size_t)TOK * H_ * 2));
    bf16_t* W11t     = (bf16_t*)(ws + alloc((size_t)E_ * I_ * H_ * 2));
    bf16_t* W12t     = (bf16_t*)(ws + alloc((size_t)E_ * I_ * H_ * 2));
    bf16_t* W2t      = (bf16_t*)(ws + alloc((size_t)E_ * I_ * H_ * 2));
    bf16_t* fusedbuf = (bf16_t*)(ws + alloc((size_t)PAIRS * I_ * 2));
    bf16_t* ybuf     = (bf16_t*)(ws + alloc((size_t)PAIRS * H_ * 2));

    static bool attr_set = false;
    if (!attr_set) {
        hipFuncSetAttribute((const void*)gemm1_kernel,
                            hipFuncAttributeMaxDynamicSharedMemorySize, 2 * G1_LDSE * 2);
        hipFuncSetAttribute((const void*)gemm2_kernel,
                            hipFuncAttributeMaxDynamicSharedMemorySize, 2 * G2_LDSE * 2);
        attr_set = true;
    }

    hipMemsetAsync(counts, 0, E_ * 4, stream);

    router_kernel<<<TOK / 4, 256, 0, stream>>>(x, Wg, top2e, top2w, counts, xb);
    scanfill_kernel<<<1, 256, 0, stream>>>(counts, offsets, blk_e, blk_m0, nblk,
                                           top2e, pair_tok, inv);
    wtrans_kernel<<<dim3(256, 24), 256, 0, stream>>>(W11, W12, W2, W11t, W12t, W2t);

    gemm1_kernel<<<dim3(I_ / 128, MAXBLK), 512, 2 * G1_LDSE * 2, stream>>>(
        xb, W11t, W12t, counts, offsets, blk_e, blk_m0, nblk, pair_tok, fusedbuf);
    gemm2_kernel<<<dim3(H_ / 128, MAXBLK), 512, 2 * G2_LDSE * 2, stream>>>(
        fusedbuf, W2t, counts, offsets, blk_e, blk_m0, nblk, ybuf);
    combine_kernel<<<TOK, 256, 0, stream>>>(ybuf, inv, top2w, out);
}